// Round 6
// baseline (179.015 us; speedup 1.0000x reference)
//
#include <hip/hip_runtime.h>

#define MWIN 2048
#define HH 8

typedef _Float16 half8 __attribute__((ext_vector_type(8)));
typedef _Float16 half4 __attribute__((ext_vector_type(4)));
typedef float f32x4 __attribute__((ext_vector_type(4)));

// XCD-chunked window swizzle: 2048 windows -> 8 chunks of 256 contiguous
// windows per XCD, so 3x3 pooling neighbors (w +-1, +-32) live in the same
// XCD L2 for both the kv_t producer and the pooling consumer.
__device__ __forceinline__ int win_swz(int bid) {
    return (bid & 7) * 256 + (bid >> 3);
}

// ---- weight prep: fragmentize Wqkv/Wproj fp32 -> MFMA-fragment fp16.
// frag[cg][ks][ct][lane] (half8): the GEMM B-load is ONE contiguous coalesced
// 1KB instruction.
__global__ __launch_bounds__(256) void k_prep_w(const float* __restrict__ Wqkv,
                                                const float* __restrict__ Wproj,
                                                _Float16* __restrict__ fq,
                                                _Float16* __restrict__ fp) {
    int tid = blockIdx.x * 256 + threadIdx.x;
    const float* src;
    _Float16* dst;
    if (tid < 6144) { src = Wqkv; dst = fq; }
    else {
        tid -= 6144;
        if (tid >= 2048) return;
        src = Wproj; dst = fp;
    }
    int lane = tid & 63, r = tid >> 6;
    int ct = r & 3, ks = (r >> 2) & 3, cg = r >> 4;
    int m = lane & 15, q = lane >> 4;
    const float* s_ = src + (size_t)(cg * 64 + ct * 16 + m) * 128 + q * 8 + ks * 32;
    float4 f0 = *(const float4*)s_;
    float4 f1 = *(const float4*)(s_ + 4);
    half8 h;
    h[0] = (_Float16)f0.x; h[1] = (_Float16)f0.y; h[2] = (_Float16)f0.z; h[3] = (_Float16)f0.w;
    h[4] = (_Float16)f1.x; h[5] = (_Float16)f1.y; h[6] = (_Float16)f1.z; h[7] = (_Float16)f1.w;
    *(half8*)(dst + (size_t)tid * 8) = h;
}

// ---- per-window fused QKV GEMM + kv/s reduction ----
// One block (512 thr = 8 waves) per window (rows are CONTIGUOUS in x).
// 1) each wave loads its A-frags straight from fp32 x (window = 20KB, L1-hot
//    after first touch) and MFMAs against fragmentized Wqkv (L2-hot) for its
//    3 col-tiles -> qkv tile lives only in LDS (relu on cols<256).
// 2) write relu'd q rows (coalesced half8) -- the only per-point output.
// 3) wave h = head h accumulates kv_t/s from LDS k,v broadcasts.
// Replaces {x-prep, 939-block GEMM (41us invariant), kv_accum} and removes
// the 61MB qkv write + 41MB re-read.
__global__ __launch_bounds__(512) void k_qkv_win(const float* __restrict__ x,
                                                 const half8* __restrict__ fq,
                                                 const int* __restrict__ offsets,
                                                 const int* __restrict__ counts,
                                                 _Float16* __restrict__ q_h,
                                                 float* __restrict__ kv_t,
                                                 float* __restrict__ s) {
    __shared__ _Float16 qk[48][392];    // row stride 784B (16B-aligned)
    int w = win_swz(blockIdx.x);
    int off = offsets[w], cnt = counts[w];
    int tid = threadIdx.x;
    int h = tid >> 6, lane = tid & 63;
    int m = lane & 15, q = lane >> 4;

    // A-fragments direct from fp32 x, rows clamped into the window
    half8 a[3][4];
    #pragma unroll
    for (int rt = 0; rt < 3; ++rt) {
        int r = rt * 16 + m;
        r = r < cnt ? r : cnt - 1;
        const float* ap = x + (size_t)(off + r) * 128 + q * 8;
        #pragma unroll
        for (int ks = 0; ks < 4; ++ks) {
            float4 f0 = *(const float4*)(ap + ks * 32);
            float4 f1 = *(const float4*)(ap + ks * 32 + 4);
            half8 hh;
            hh[0] = (_Float16)f0.x; hh[1] = (_Float16)f0.y;
            hh[2] = (_Float16)f0.z; hh[3] = (_Float16)f0.w;
            hh[4] = (_Float16)f1.x; hh[5] = (_Float16)f1.y;
            hh[6] = (_Float16)f1.z; hh[7] = (_Float16)f1.w;
            a[rt][ks] = hh;
        }
    }

    // wave h owns col-tiles ctg = 3h..3h+2 (24 tiles = 384 cols)
    #pragma unroll
    for (int j = 0; j < 3; ++j) {
        int ctg = h * 3 + j;
        int cg = ctg >> 2, ctl = ctg & 3;
        half8 bfr[4];
        #pragma unroll
        for (int ks = 0; ks < 4; ++ks)
            bfr[ks] = fq[((size_t)cg * 16 + ks * 4 + ctl) * 64 + lane];
        bool dorelu = ctg < 16;   // cols < 256 = q,k
        #pragma unroll
        for (int rt = 0; rt < 3; ++rt) {
            f32x4 acc = {};
            #pragma unroll
            for (int ks = 0; ks < 4; ++ks)
                acc = __builtin_amdgcn_mfma_f32_16x16x32_f16(a[rt][ks], bfr[ks], acc, 0, 0, 0);
            #pragma unroll
            for (int reg = 0; reg < 4; ++reg) {
                float vv = acc[reg];
                if (dorelu) vv = fmaxf(vv, 0.f);
                qk[rt * 16 + q * 4 + reg][ctg * 16 + m] = (_Float16)vv;
            }
        }
    }
    __syncthreads();

    // relu'd q rows -> global (coalesced half8; 16 half8 per row)
    #pragma unroll
    for (int it = 0; it < 2; ++it) {
        int idx = it * 512 + tid;
        int row = idx >> 4, c8 = idx & 15;
        if (row < cnt)
            *(half8*)(q_h + (size_t)(off + row) * 128 + c8 * 8) = *(const half8*)&qk[row][c8 * 8];
    }

    // kv/s accumulation: wave h = head h, LDS broadcast reads
    int d = lane & 15, eq = lane >> 4;
    float a0 = 0.f, a1 = 0.f, a2 = 0.f, a3 = 0.f, sa = 0.f;
    for (int p = 0; p < cnt; ++p) {
        float kk = (float)qk[p][128 + h * 16 + d];
        half4 v4 = *(const half4*)&qk[p][256 + h * 16 + eq * 4];
        a0 += kk * (float)v4[0];
        a1 += kk * (float)v4[1];
        a2 += kk * (float)v4[2];
        a3 += kk * (float)v4[3];
        sa += kk;
    }
    float* o = kv_t + (((size_t)(w * HH + h)) << 8);
    o[(eq * 4 + 0) * 16 + d] = a0;
    o[(eq * 4 + 1) * 16 + d] = a1;
    o[(eq * 4 + 2) * 16 + d] = a2;
    o[(eq * 4 + 3) * 16 + d] = a3;
    if (eq == 0) s[(((size_t)(w * HH + h)) << 4) + d] = sa;
}

// ---------------- fused attn + 3x3 pool + output projection ----------------
// One block (512 thr = 8 waves) per window. Wave h: pool kv/s from 9 neighbor
// windows (same-XCD L2 via win_swz), attention MFMA -> y-slice into LDS.
// Barrier. 8 waves do the [48x128]x[128x128] proj GEMM from LDS with
// fragmentized Wproj, stage to LDS, store rows<cnt coalesced + bias.
__global__ __launch_bounds__(512) void k_attn_proj(const _Float16* __restrict__ q_h,
                                                   const float* __restrict__ kv_t,
                                                   const float* __restrict__ s,
                                                   const half8* __restrict__ fp,
                                                   const float* __restrict__ bproj,
                                                   const int* __restrict__ offsets,
                                                   const int* __restrict__ counts,
                                                   float* __restrict__ out) {
    __shared__ _Float16 y_t[48][136];
    __shared__ float o_t[48][132];
    int w = win_swz(blockIdx.x);
    int h = threadIdx.x >> 6;
    int lane = threadIdx.x & 63;
    int col = lane & 15;
    int kq = lane >> 4;
    int off = offsets[w], cnt = counts[w];
    bool klive = kq < 2;
    int koff = (kq & 1) * 8;

    int b = w >> 10, yy = (w >> 5) & 31, xx = w & 31;
    f32x4 k0 = {}, k1 = {}, s0 = {}, s1 = {};
    if (klive) {
        #pragma unroll
        for (int dy = -1; dy <= 1; ++dy)
            #pragma unroll
            for (int dx = -1; dx <= 1; ++dx) {
                int ny = yy + dy, nx = xx + dx;
                if (ny < 0 || ny >= 32 || nx < 0 || nx >= 32) continue;
                int nw = (b << 10) | (ny << 5) | nx;
                const float* kb = kv_t + (((size_t)(nw * HH + h)) << 8) + col * 16 + koff;
                k0 += *(const f32x4*)kb;
                k1 += *(const f32x4*)(kb + 4);
                const float* sb = s + (((size_t)(nw * HH + h)) << 4) + koff;
                s0 += *(const f32x4*)sb;
                s1 += *(const f32x4*)(sb + 4);
            }
    }
    half8 a_kv, a_s;
    #pragma unroll
    for (int i = 0; i < 4; ++i) {
        a_kv[i] = (_Float16)k0[i]; a_kv[4 + i] = (_Float16)k1[i];
        a_s[i]  = (_Float16)s0[i]; a_s[4 + i]  = (_Float16)s1[i];
    }

    #pragma unroll
    for (int c = 0; c < 3; ++c) {
        int p = c * 16 + col;
        int pc = p < cnt ? p : cnt - 1;
        half8 b_q = *(const half8*)(q_h + (size_t)(off + pc) * 128 + h * 16 + koff);
        f32x4 acc = {};
        acc = __builtin_amdgcn_mfma_f32_16x16x32_f16(a_kv, b_q, acc, 0, 0, 0);
        f32x4 accs = {};
        accs = __builtin_amdgcn_mfma_f32_16x16x32_f16(a_s, b_q, accs, 0, 0, 0);
        float zinv = 1.f / (accs[0] + 1e-6f);
        half4 yo;
        #pragma unroll
        for (int i = 0; i < 4; ++i) yo[i] = (_Float16)(acc[i] * zinv);
        *(half4*)&y_t[p][h * 16 + kq * 4] = yo;
    }
    __syncthreads();

    int m = col, q = kq;
    int ct = h;
    int cg = ct >> 2, ctl = ct & 3;
    half8 bfr[4];
    #pragma unroll
    for (int ks = 0; ks < 4; ++ks)
        bfr[ks] = fp[((size_t)cg * 16 + ks * 4 + ctl) * 64 + lane];
    float bv = bproj[ct * 16 + m];
    #pragma unroll
    for (int rt = 0; rt < 3; ++rt) {
        f32x4 acc = (f32x4){bv, bv, bv, bv};
        #pragma unroll
        for (int ks = 0; ks < 4; ++ks) {
            half8 af = *(const half8*)&y_t[rt * 16 + m][q * 8 + ks * 32];
            acc = __builtin_amdgcn_mfma_f32_16x16x32_f16(af, bfr[ks], acc, 0, 0, 0);
        }
        #pragma unroll
        for (int reg = 0; reg < 4; ++reg)
            o_t[rt * 16 + q * 4 + reg][ct * 16 + m] = acc[reg];
    }
    __syncthreads();

    #pragma unroll
    for (int it = 0; it < 3; ++it) {
        int j = it * 512 + threadIdx.x;
        int r = j >> 5, c4 = j & 31;
        if (r < cnt)
            *(float4*)(out + ((size_t)(off + r) << 7) + c4 * 4) = *(const float4*)&o_t[r][c4 * 4];
    }
}

extern "C" void kernel_launch(void* const* d_in, const int* in_sizes, int n_in,
                              void* d_out, int out_size, void* d_ws, size_t ws_size,
                              hipStream_t stream) {
    const float* x     = (const float*)d_in[0];
    const float* Wqkv  = (const float*)d_in[1];
    const float* Wproj = (const float*)d_in[2];
    const float* bproj = (const float*)d_in[3];
    const int*   offsets = (const int*)d_in[4];
    const int*   counts  = (const int*)d_in[5];

    int N = in_sizes[0] / 128;

    char* ws = (char*)d_ws;
    float* kv_t = (float*)ws;                                    ws += (size_t)MWIN * HH * 256 * 4;
    float* s    = (float*)ws;                                    ws += (size_t)MWIN * HH * 16 * 4;
    _Float16* q_h    = (_Float16*)ws;                            ws += (size_t)N * 128 * 2;
    _Float16* fq     = (_Float16*)ws;                            ws += (size_t)6144 * 8 * 2;
    _Float16* fp     = (_Float16*)ws;                            ws += (size_t)2048 * 8 * 2;
    float* out  = (float*)d_out;

    k_prep_w<<<32, 256, 0, stream>>>(Wqkv, Wproj, fq, fp);

    k_qkv_win<<<MWIN, 512, 0, stream>>>(x, (const half8*)fq, offsets, counts,
                                        q_h, kv_t, s);

    k_attn_proj<<<MWIN, 512, 0, stream>>>(q_h, kv_t, s, (const half8*)fp, bproj,
                                          offsets, counts, out);
}

// Round 7
// 153.433 us; speedup vs baseline: 1.1667x; 1.1667x over previous
//
#include <hip/hip_runtime.h>

#define MWIN 2048
#define HH 8

typedef _Float16 half8 __attribute__((ext_vector_type(8)));
typedef _Float16 half4 __attribute__((ext_vector_type(4)));
typedef float f32x4 __attribute__((ext_vector_type(4)));

// XCD-chunked window swizzle: 2048 windows -> 8 chunks of 256 contiguous
// windows per XCD, so 3x3 pooling neighbors (w +-1, +-32) live in the same
// XCD L2 for both the kv_t producer and the pooling consumer.
__device__ __forceinline__ int win_swz(int bid) {
    return (bid & 7) * 256 + (bid >> 3);
}

// ---- weight prep: fragmentize Wqkv/Wproj fp32 -> MFMA-fragment fp16.
// frag[cg][ks][ct][lane] (half8): the GEMM B-load is ONE contiguous coalesced
// 1KB instruction.
__global__ __launch_bounds__(256) void k_prep_w(const float* __restrict__ Wqkv,
                                                const float* __restrict__ Wproj,
                                                _Float16* __restrict__ fq,
                                                _Float16* __restrict__ fp) {
    int tid = blockIdx.x * 256 + threadIdx.x;
    const float* src;
    _Float16* dst;
    if (tid < 6144) { src = Wqkv; dst = fq; }
    else {
        tid -= 6144;
        if (tid >= 2048) return;
        src = Wproj; dst = fp;
    }
    int lane = tid & 63, r = tid >> 6;
    int ct = r & 3, ks = (r >> 2) & 3, cg = r >> 4;
    int m = lane & 15, q = lane >> 4;
    const float* s_ = src + (size_t)(cg * 64 + ct * 16 + m) * 128 + q * 8 + ks * 32;
    float4 f0 = *(const float4*)s_;
    float4 f1 = *(const float4*)(s_ + 4);
    half8 h;
    h[0] = (_Float16)f0.x; h[1] = (_Float16)f0.y; h[2] = (_Float16)f0.z; h[3] = (_Float16)f0.w;
    h[4] = (_Float16)f1.x; h[5] = (_Float16)f1.y; h[6] = (_Float16)f1.z; h[7] = (_Float16)f1.w;
    *(half8*)(dst + (size_t)tid * 8) = h;
}

// ---- per-window fused QKV GEMM + kv/s reduction ----
// One block (512 thr = 8 waves) per window.
// ROUND-7 FIX: x window is staged to LDS ONCE by all 512 threads (coalesced
// float4, 3/thread, converted once) instead of every wave gathering+converting
// the same 20KB redundantly (r6: 24 strided 32-line gathers + 96 cvt PER
// THREAD -> VALUBusy 30%, 64us). A-frags then come from ds_read_b128 with
// even 8-words/bank distribution (272B row stride).
__global__ __launch_bounds__(512) void k_qkv_win(const float* __restrict__ x,
                                                 const half8* __restrict__ fq,
                                                 const int* __restrict__ offsets,
                                                 const int* __restrict__ counts,
                                                 _Float16* __restrict__ q_h,
                                                 float* __restrict__ kv_t,
                                                 float* __restrict__ s) {
    __shared__ _Float16 xs[48][136];    // row stride 272B (16B-aligned)
    __shared__ _Float16 qk[48][392];    // row stride 784B (16B-aligned)
    int w = win_swz(blockIdx.x);
    int off = offsets[w], cnt = counts[w];
    int tid = threadIdx.x;

    // cooperative coalesced stage: 48 rows x 32 float4 = 1536 float4
    #pragma unroll
    for (int it = 0; it < 3; ++it) {
        int j = it * 512 + tid;
        int row = j >> 5, c4 = j & 31;
        int sr = row < cnt ? row : cnt - 1;
        float4 f = *(const float4*)(x + (size_t)(off + sr) * 128 + c4 * 4);
        half4 hv;
        hv[0] = (_Float16)f.x; hv[1] = (_Float16)f.y;
        hv[2] = (_Float16)f.z; hv[3] = (_Float16)f.w;
        *(half4*)&xs[row][c4 * 4] = hv;
    }
    __syncthreads();

    int h = tid >> 6, lane = tid & 63;
    int m = lane & 15, q = lane >> 4;

    // A fragments from LDS (even bank distribution: 8 words/bank = b128 min)
    half8 a[3][4];
    #pragma unroll
    for (int rt = 0; rt < 3; ++rt)
        #pragma unroll
        for (int ks = 0; ks < 4; ++ks)
            a[rt][ks] = *(const half8*)&xs[rt * 16 + m][q * 8 + ks * 32];

    // wave h owns col-tiles ctg = 3h..3h+2 (24 tiles = 384 cols)
    #pragma unroll
    for (int j = 0; j < 3; ++j) {
        int ctg = h * 3 + j;
        int cg = ctg >> 2, ctl = ctg & 3;
        half8 bfr[4];
        #pragma unroll
        for (int ks = 0; ks < 4; ++ks)
            bfr[ks] = fq[((size_t)cg * 16 + ks * 4 + ctl) * 64 + lane];
        bool dorelu = ctg < 16;   // cols < 256 = q,k
        #pragma unroll
        for (int rt = 0; rt < 3; ++rt) {
            f32x4 acc = {};
            #pragma unroll
            for (int ks = 0; ks < 4; ++ks)
                acc = __builtin_amdgcn_mfma_f32_16x16x32_f16(a[rt][ks], bfr[ks], acc, 0, 0, 0);
            #pragma unroll
            for (int reg = 0; reg < 4; ++reg) {
                float vv = acc[reg];
                if (dorelu) vv = fmaxf(vv, 0.f);
                qk[rt * 16 + q * 4 + reg][ctg * 16 + m] = (_Float16)vv;
            }
        }
    }
    __syncthreads();

    // relu'd q rows -> global (coalesced half8; 16 half8 per row)
    #pragma unroll
    for (int it = 0; it < 2; ++it) {
        int idx = it * 512 + tid;
        int row = idx >> 4, c8 = idx & 15;
        if (row < cnt)
            *(half8*)(q_h + (size_t)(off + row) * 128 + c8 * 8) = *(const half8*)&qk[row][c8 * 8];
    }

    // kv/s accumulation: wave h = head h, LDS broadcast reads
    int d = lane & 15, eq = lane >> 4;
    float a0 = 0.f, a1 = 0.f, a2 = 0.f, a3 = 0.f, sa = 0.f;
    for (int p = 0; p < cnt; ++p) {
        float kk = (float)qk[p][128 + h * 16 + d];
        half4 v4 = *(const half4*)&qk[p][256 + h * 16 + eq * 4];
        a0 += kk * (float)v4[0];
        a1 += kk * (float)v4[1];
        a2 += kk * (float)v4[2];
        a3 += kk * (float)v4[3];
        sa += kk;
    }
    float* o = kv_t + (((size_t)(w * HH + h)) << 8);
    o[(eq * 4 + 0) * 16 + d] = a0;
    o[(eq * 4 + 1) * 16 + d] = a1;
    o[(eq * 4 + 2) * 16 + d] = a2;
    o[(eq * 4 + 3) * 16 + d] = a3;
    if (eq == 0) s[(((size_t)(w * HH + h)) << 4) + d] = sa;
}

// ---------------- fused attn + 3x3 pool + output projection ----------------
// One block (512 thr = 8 waves) per window. Wave h: pool kv/s from 9 neighbor
// windows (same-XCD L2 via win_swz), attention MFMA -> y-slice into LDS.
// Barrier. 8 waves do the [48x128]x[128x128] proj GEMM from LDS with
// fragmentized Wproj, stage to LDS, store rows<cnt coalesced + bias.
__global__ __launch_bounds__(512) void k_attn_proj(const _Float16* __restrict__ q_h,
                                                   const float* __restrict__ kv_t,
                                                   const float* __restrict__ s,
                                                   const half8* __restrict__ fp,
                                                   const float* __restrict__ bproj,
                                                   const int* __restrict__ offsets,
                                                   const int* __restrict__ counts,
                                                   float* __restrict__ out) {
    __shared__ _Float16 y_t[48][136];
    __shared__ float o_t[48][132];
    int w = win_swz(blockIdx.x);
    int h = threadIdx.x >> 6;
    int lane = threadIdx.x & 63;
    int col = lane & 15;
    int kq = lane >> 4;
    int off = offsets[w], cnt = counts[w];
    bool klive = kq < 2;
    int koff = (kq & 1) * 8;

    int b = w >> 10, yy = (w >> 5) & 31, xx = w & 31;
    f32x4 k0 = {}, k1 = {}, s0 = {}, s1 = {};
    if (klive) {
        #pragma unroll
        for (int dy = -1; dy <= 1; ++dy)
            #pragma unroll
            for (int dx = -1; dx <= 1; ++dx) {
                int ny = yy + dy, nx = xx + dx;
                if (ny < 0 || ny >= 32 || nx < 0 || nx >= 32) continue;
                int nw = (b << 10) | (ny << 5) | nx;
                const float* kb = kv_t + (((size_t)(nw * HH + h)) << 8) + col * 16 + koff;
                k0 += *(const f32x4*)kb;
                k1 += *(const f32x4*)(kb + 4);
                const float* sb = s + (((size_t)(nw * HH + h)) << 4) + koff;
                s0 += *(const f32x4*)sb;
                s1 += *(const f32x4*)(sb + 4);
            }
    }
    half8 a_kv, a_s;
    #pragma unroll
    for (int i = 0; i < 4; ++i) {
        a_kv[i] = (_Float16)k0[i]; a_kv[4 + i] = (_Float16)k1[i];
        a_s[i]  = (_Float16)s0[i]; a_s[4 + i]  = (_Float16)s1[i];
    }

    #pragma unroll
    for (int c = 0; c < 3; ++c) {
        int p = c * 16 + col;
        int pc = p < cnt ? p : cnt - 1;
        half8 b_q = *(const half8*)(q_h + (size_t)(off + pc) * 128 + h * 16 + koff);
        f32x4 acc = {};
        acc = __builtin_amdgcn_mfma_f32_16x16x32_f16(a_kv, b_q, acc, 0, 0, 0);
        f32x4 accs = {};
        accs = __builtin_amdgcn_mfma_f32_16x16x32_f16(a_s, b_q, accs, 0, 0, 0);
        float zinv = 1.f / (accs[0] + 1e-6f);
        half4 yo;
        #pragma unroll
        for (int i = 0; i < 4; ++i) yo[i] = (_Float16)(acc[i] * zinv);
        *(half4*)&y_t[p][h * 16 + kq * 4] = yo;
    }
    __syncthreads();

    int m = col, q = kq;
    int ct = h;
    int cg = ct >> 2, ctl = ct & 3;
    half8 bfr[4];
    #pragma unroll
    for (int ks = 0; ks < 4; ++ks)
        bfr[ks] = fp[((size_t)cg * 16 + ks * 4 + ctl) * 64 + lane];
    float bv = bproj[ct * 16 + m];
    #pragma unroll
    for (int rt = 0; rt < 3; ++rt) {
        f32x4 acc = (f32x4){bv, bv, bv, bv};
        #pragma unroll
        for (int ks = 0; ks < 4; ++ks) {
            half8 af = *(const half8*)&y_t[rt * 16 + m][q * 8 + ks * 32];
            acc = __builtin_amdgcn_mfma_f32_16x16x32_f16(af, bfr[ks], acc, 0, 0, 0);
        }
        #pragma unroll
        for (int reg = 0; reg < 4; ++reg)
            o_t[rt * 16 + q * 4 + reg][ct * 16 + m] = acc[reg];
    }
    __syncthreads();

    #pragma unroll
    for (int it = 0; it < 3; ++it) {
        int j = it * 512 + threadIdx.x;
        int r = j >> 5, c4 = j & 31;
        if (r < cnt)
            *(float4*)(out + ((size_t)(off + r) << 7) + c4 * 4) = *(const float4*)&o_t[r][c4 * 4];
    }
}

extern "C" void kernel_launch(void* const* d_in, const int* in_sizes, int n_in,
                              void* d_out, int out_size, void* d_ws, size_t ws_size,
                              hipStream_t stream) {
    const float* x     = (const float*)d_in[0];
    const float* Wqkv  = (const float*)d_in[1];
    const float* Wproj = (const float*)d_in[2];
    const float* bproj = (const float*)d_in[3];
    const int*   offsets = (const int*)d_in[4];
    const int*   counts  = (const int*)d_in[5];

    int N = in_sizes[0] / 128;

    char* ws = (char*)d_ws;
    float* kv_t = (float*)ws;                                    ws += (size_t)MWIN * HH * 256 * 4;
    float* s    = (float*)ws;                                    ws += (size_t)MWIN * HH * 16 * 4;
    _Float16* q_h    = (_Float16*)ws;                            ws += (size_t)N * 128 * 2;
    _Float16* fq     = (_Float16*)ws;                            ws += (size_t)6144 * 8 * 2;
    _Float16* fp     = (_Float16*)ws;                            ws += (size_t)2048 * 8 * 2;
    float* out  = (float*)d_out;

    k_prep_w<<<32, 256, 0, stream>>>(Wqkv, Wproj, fq, fp);

    k_qkv_win<<<MWIN, 512, 0, stream>>>(x, (const half8*)fq, offsets, counts,
                                        q_h, kv_t, s);

    k_attn_proj<<<MWIN, 512, 0, stream>>>(q_h, kv_t, s, (const half8*)fp, bproj,
                                          offsets, counts, out);
}

// Round 8
// 150.337 us; speedup vs baseline: 1.1908x; 1.0206x over previous
//
#include <hip/hip_runtime.h>

#define MWIN 2048
#define HH 8

typedef _Float16 half8 __attribute__((ext_vector_type(8)));
typedef _Float16 half4 __attribute__((ext_vector_type(4)));
typedef float f32x4 __attribute__((ext_vector_type(4)));

// XCD-chunked window swizzle: 3x3 pooling neighbors (w +-1, +-32) stay in the
// same XCD L2 for both producer and consumer kernels.
__device__ __forceinline__ int win_swz(int bid) {
    return (bid & 7) * 256 + (bid >> 3);
}

// ---- weight prep: fragmentize Wqkv/Wproj fp32 -> MFMA-fragment fp16.
__global__ __launch_bounds__(256) void k_prep_w(const float* __restrict__ Wqkv,
                                                const float* __restrict__ Wproj,
                                                _Float16* __restrict__ fq,
                                                _Float16* __restrict__ fp) {
    int tid = blockIdx.x * 256 + threadIdx.x;
    const float* src;
    _Float16* dst;
    if (tid < 6144) { src = Wqkv; dst = fq; }
    else {
        tid -= 6144;
        if (tid >= 2048) return;
        src = Wproj; dst = fp;
    }
    int lane = tid & 63, r = tid >> 6;
    int ct = r & 3, ks = (r >> 2) & 3, cg = r >> 4;
    int m = lane & 15, q = lane >> 4;
    const float* s_ = src + (size_t)(cg * 64 + ct * 16 + m) * 128 + q * 8 + ks * 32;
    float4 f0 = *(const float4*)s_;
    float4 f1 = *(const float4*)(s_ + 4);
    half8 h;
    h[0] = (_Float16)f0.x; h[1] = (_Float16)f0.y; h[2] = (_Float16)f0.z; h[3] = (_Float16)f0.w;
    h[4] = (_Float16)f1.x; h[5] = (_Float16)f1.y; h[6] = (_Float16)f1.z; h[7] = (_Float16)f1.w;
    *(half8*)(dst + (size_t)tid * 8) = h;
}

// ---- per-window fused QKV GEMM + kv/s reduction ----
// One block (512 thr = 8 waves) per window.
// ROUND-8: kv/s accumulation MFMA-ized. The GEMM phase stores k,v TRANSPOSED
// in LDS (kT[h][d][p], vT[h][e][p], positions >= cnt zeroed for k, 48..63
// zero-filled) so kv = K^T V is 2 mfma_16x16x32 and s = K^T 1 is 2 more with
// a ones B-operand -- replacing the 40-iteration serial VALU loop (~400 inst
// per wave -> ~15). kT/vT union the dead xs staging buffer.
__global__ __launch_bounds__(512) void k_qkv_win(const float* __restrict__ x,
                                                 const half8* __restrict__ fq,
                                                 const int* __restrict__ offsets,
                                                 const int* __restrict__ counts,
                                                 _Float16* __restrict__ q_h,
                                                 float* __restrict__ kv_t,
                                                 float* __restrict__ s) {
    // ubuf: phase A = xs[48][136] staging (13KB); phase B = kT+vT [8][16][72]x2
    __shared__ __attribute__((aligned(16))) _Float16 ubuf[18432];
    __shared__ __attribute__((aligned(16))) _Float16 q_lds[48][136];
    _Float16 (*kT)[16][72] = (_Float16(*)[16][72])ubuf;
    _Float16 (*vT)[16][72] = (_Float16(*)[16][72])(ubuf + 9216);

    int w = win_swz(blockIdx.x);
    int off = offsets[w], cnt = counts[w];
    int tid = threadIdx.x;

    // phase A: cooperative coalesced stage of x (48 rows x 32 float4)
    #pragma unroll
    for (int it = 0; it < 3; ++it) {
        int j = it * 512 + tid;
        int row = j >> 5, c4 = j & 31;
        int sr = row < cnt ? row : cnt - 1;
        float4 f = *(const float4*)(x + (size_t)(off + sr) * 128 + c4 * 4);
        half4 hv;
        hv[0] = (_Float16)f.x; hv[1] = (_Float16)f.y;
        hv[2] = (_Float16)f.z; hv[3] = (_Float16)f.w;
        *(half4*)&ubuf[row * 136 + c4 * 4] = hv;
    }
    __syncthreads();

    int h = tid >> 6, lane = tid & 63;
    int m = lane & 15, q = lane >> 4;

    // A fragments from LDS into registers (xs dead afterwards)
    half8 a[3][4];
    #pragma unroll
    for (int rt = 0; rt < 3; ++rt)
        #pragma unroll
        for (int ks = 0; ks < 4; ++ks)
            a[rt][ks] = *(const half8*)&ubuf[(rt * 16 + m) * 136 + q * 8 + ks * 32];
    __syncthreads();   // all xs reads done; ubuf becomes kT/vT

    // zero-fill kT/vT positions 48..63 (one half4 each per thread)
    {
        int zh = tid >> 6, zd = (tid >> 2) & 15, zp = 48 + (tid & 3) * 4;
        *(half4*)&kT[zh][zd][zp] = (half4){};
        *(half4*)&vT[zh][zd][zp] = (half4){};
    }

    // phase B: GEMM. wave h owns col-tiles ctg = 3h..3h+2
    #pragma unroll
    for (int j = 0; j < 3; ++j) {
        int ctg = h * 3 + j;
        int cg = ctg >> 2, ctl = ctg & 3;
        half8 bfr[4];
        #pragma unroll
        for (int ks = 0; ks < 4; ++ks)
            bfr[ks] = fq[((size_t)cg * 16 + ks * 4 + ctl) * 64 + lane];
        #pragma unroll
        for (int rt = 0; rt < 3; ++rt) {
            f32x4 acc = {};
            #pragma unroll
            for (int ks = 0; ks < 4; ++ks)
                acc = __builtin_amdgcn_mfma_f32_16x16x32_f16(a[rt][ks], bfr[ks], acc, 0, 0, 0);
            int p0 = rt * 16 + q * 4;
            if (ctg < 8) {              // q cols: relu, row-major for q_h store
                #pragma unroll
                for (int reg = 0; reg < 4; ++reg)
                    q_lds[p0 + reg][ctg * 16 + m] = (_Float16)fmaxf(acc[reg], 0.f);
            } else if (ctg < 16) {      // k cols: relu + zero p>=cnt, transposed
                int head = ctg - 8;
                half4 hv;
                #pragma unroll
                for (int reg = 0; reg < 4; ++reg)
                    hv[reg] = (_Float16)((p0 + reg < cnt) ? fmaxf(acc[reg], 0.f) : 0.f);
                *(half4*)&kT[head][m][p0] = hv;
            } else {                    // v cols: transposed
                int head = ctg - 16;
                half4 hv;
                #pragma unroll
                for (int reg = 0; reg < 4; ++reg) hv[reg] = (_Float16)acc[reg];
                *(half4*)&vT[head][m][p0] = hv;
            }
        }
    }
    __syncthreads();

    // relu'd q rows -> global (coalesced half8)
    #pragma unroll
    for (int it = 0; it < 2; ++it) {
        int idx = it * 512 + tid;
        int row = idx >> 4, c8 = idx & 15;
        if (row < cnt)
            *(half8*)(q_h + (size_t)(off + row) * 128 + c8 * 8) = *(const half8*)&q_lds[row][c8 * 8];
    }

    // kv = K^T V, s = K^T 1 via MFMA; wave h = head h
    half8 a1 = *(const half8*)&kT[h][m][q * 8];
    half8 a2 = *(const half8*)&kT[h][m][32 + q * 8];
    half8 b1 = *(const half8*)&vT[h][m][q * 8];
    half8 b2 = *(const half8*)&vT[h][m][32 + q * 8];
    half8 ones;
    #pragma unroll
    for (int i = 0; i < 8; ++i) ones[i] = (_Float16)1.0f;
    f32x4 kva = {};
    kva = __builtin_amdgcn_mfma_f32_16x16x32_f16(a1, b1, kva, 0, 0, 0);
    kva = __builtin_amdgcn_mfma_f32_16x16x32_f16(a2, b2, kva, 0, 0, 0);
    f32x4 sa4 = {};
    sa4 = __builtin_amdgcn_mfma_f32_16x16x32_f16(a1, ones, sa4, 0, 0, 0);
    sa4 = __builtin_amdgcn_mfma_f32_16x16x32_f16(a2, ones, sa4, 0, 0, 0);
    // acc lane: C[row=d=q*4+reg][col=e=m] -> kv_t layout [e][d]: one float4
    *(f32x4*)(kv_t + (((size_t)(w * HH + h)) << 8) + m * 16 + q * 4) = kva;
    if (m == 0)
        *(f32x4*)(s + (((size_t)(w * HH + h)) << 4) + q * 4) = sa4;
}

// ---------------- fused attn + 3x3 pool + output projection ----------------
__global__ __launch_bounds__(512) void k_attn_proj(const _Float16* __restrict__ q_h,
                                                   const float* __restrict__ kv_t,
                                                   const float* __restrict__ s,
                                                   const half8* __restrict__ fp,
                                                   const float* __restrict__ bproj,
                                                   const int* __restrict__ offsets,
                                                   const int* __restrict__ counts,
                                                   float* __restrict__ out) {
    __shared__ _Float16 y_t[48][136];
    __shared__ float o_t[48][132];
    int w = win_swz(blockIdx.x);
    int h = threadIdx.x >> 6;
    int lane = threadIdx.x & 63;
    int col = lane & 15;
    int kq = lane >> 4;
    int off = offsets[w], cnt = counts[w];
    bool klive = kq < 2;
    int koff = (kq & 1) * 8;

    int b = w >> 10, yy = (w >> 5) & 31, xx = w & 31;
    f32x4 k0 = {}, k1 = {}, s0 = {}, s1 = {};
    if (klive) {
        #pragma unroll
        for (int dy = -1; dy <= 1; ++dy)
            #pragma unroll
            for (int dx = -1; dx <= 1; ++dx) {
                int ny = yy + dy, nx = xx + dx;
                if (ny < 0 || ny >= 32 || nx < 0 || nx >= 32) continue;
                int nw = (b << 10) | (ny << 5) | nx;
                const float* kb = kv_t + (((size_t)(nw * HH + h)) << 8) + col * 16 + koff;
                k0 += *(const f32x4*)kb;
                k1 += *(const f32x4*)(kb + 4);
                const float* sb = s + (((size_t)(nw * HH + h)) << 4) + koff;
                s0 += *(const f32x4*)sb;
                s1 += *(const f32x4*)(sb + 4);
            }
    }
    half8 a_kv, a_s;
    #pragma unroll
    for (int i = 0; i < 4; ++i) {
        a_kv[i] = (_Float16)k0[i]; a_kv[4 + i] = (_Float16)k1[i];
        a_s[i]  = (_Float16)s0[i]; a_s[4 + i]  = (_Float16)s1[i];
    }

    #pragma unroll
    for (int c = 0; c < 3; ++c) {
        int p = c * 16 + col;
        int pc = p < cnt ? p : cnt - 1;
        half8 b_q = *(const half8*)(q_h + (size_t)(off + pc) * 128 + h * 16 + koff);
        f32x4 acc = {};
        acc = __builtin_amdgcn_mfma_f32_16x16x32_f16(a_kv, b_q, acc, 0, 0, 0);
        f32x4 accs = {};
        accs = __builtin_amdgcn_mfma_f32_16x16x32_f16(a_s, b_q, accs, 0, 0, 0);
        float zinv = 1.f / (accs[0] + 1e-6f);
        half4 yo;
        #pragma unroll
        for (int i = 0; i < 4; ++i) yo[i] = (_Float16)(acc[i] * zinv);
        *(half4*)&y_t[p][h * 16 + kq * 4] = yo;
    }
    __syncthreads();

    int m = col, q = kq;
    int ct = h;
    int cg = ct >> 2, ctl = ct & 3;
    half8 bfr[4];
    #pragma unroll
    for (int ks = 0; ks < 4; ++ks)
        bfr[ks] = fp[((size_t)cg * 16 + ks * 4 + ctl) * 64 + lane];
    float bv = bproj[ct * 16 + m];
    #pragma unroll
    for (int rt = 0; rt < 3; ++rt) {
        f32x4 acc = (f32x4){bv, bv, bv, bv};
        #pragma unroll
        for (int ks = 0; ks < 4; ++ks) {
            half8 af = *(const half8*)&y_t[rt * 16 + m][q * 8 + ks * 32];
            acc = __builtin_amdgcn_mfma_f32_16x16x32_f16(af, bfr[ks], acc, 0, 0, 0);
        }
        #pragma unroll
        for (int reg = 0; reg < 4; ++reg)
            o_t[rt * 16 + q * 4 + reg][ct * 16 + m] = acc[reg];
    }
    __syncthreads();

    #pragma unroll
    for (int it = 0; it < 3; ++it) {
        int j = it * 512 + threadIdx.x;
        int r = j >> 5, c4 = j & 31;
        if (r < cnt)
            *(float4*)(out + ((size_t)(off + r) << 7) + c4 * 4) = *(const float4*)&o_t[r][c4 * 4];
    }
}

extern "C" void kernel_launch(void* const* d_in, const int* in_sizes, int n_in,
                              void* d_out, int out_size, void* d_ws, size_t ws_size,
                              hipStream_t stream) {
    const float* x     = (const float*)d_in[0];
    const float* Wqkv  = (const float*)d_in[1];
    const float* Wproj = (const float*)d_in[2];
    const float* bproj = (const float*)d_in[3];
    const int*   offsets = (const int*)d_in[4];
    const int*   counts  = (const int*)d_in[5];

    int N = in_sizes[0] / 128;

    char* ws = (char*)d_ws;
    float* kv_t = (float*)ws;                                    ws += (size_t)MWIN * HH * 256 * 4;
    float* s    = (float*)ws;                                    ws += (size_t)MWIN * HH * 16 * 4;
    _Float16* q_h    = (_Float16*)ws;                            ws += (size_t)N * 128 * 2;
    _Float16* fq     = (_Float16*)ws;                            ws += (size_t)6144 * 8 * 2;
    _Float16* fp     = (_Float16*)ws;                            ws += (size_t)2048 * 8 * 2;
    float* out  = (float*)d_out;

    k_prep_w<<<32, 256, 0, stream>>>(Wqkv, Wproj, fq, fp);

    k_qkv_win<<<MWIN, 512, 0, stream>>>(x, (const half8*)fq, offsets, counts,
                                        q_h, kv_t, s);

    k_attn_proj<<<MWIN, 512, 0, stream>>>(q_h, kv_t, s, (const half8*)fp, bproj,
                                          offsets, counts, out);
}